// Round 15
// baseline (228.447 us; speedup 1.0000x reference)
//
#include <hip/hip_runtime.h>
#include <hip/hip_fp16.h>

typedef _Float16 half8 __attribute__((ext_vector_type(8)));
typedef _Float16 half4v __attribute__((ext_vector_type(4)));
typedef float f32x4 __attribute__((ext_vector_type(4)));

static constexpr int B_ = 8, T_ = 64, N_ = 256;
static constexpr int F0 = 12, F1 = 64, F2 = 32;
static constexpr int BT_ = B_ * T_;
// packed ST: per bt, 256 rows x 32 m-chunks x (8 hi | 8 lo) halfs = 256 KB
static constexpr size_t STPK_BT = (size_t)N_ * 32 * 16;

__device__ inline float tanh_fast(float x) {
    x = fminf(20.f, fmaxf(-20.f, x));
    float e = __expf(2.f * x);
    return (e - 1.f) / (e + 1.f);
}

// ---------------- K0: fused S-transpose + U1 = x(t-1)@S(t) ------------------
// grid (BT,4): block owns 64 output rows (n = S columns), 2 m-tiles of 128.
// Register-staged NT loads; packed hi/lo ST store (adjacent 16B pairs).
__global__ __launch_bounds__(256) void k_transpose_u1(
    const float* __restrict__ S, const float* __restrict__ x,
    _Float16* __restrict__ STpk,
    _Float16* __restrict__ U1h, _Float16* __restrict__ U1l,
    _Float16* __restrict__ U1Th, _Float16* __restrict__ U1Tl) {
    __shared__ float tile[64][129];   // 33 KB
    int bt = blockIdx.x;
    int t  = bt & (T_ - 1);
    int n0 = blockIdx.y * 64;
    const float* s = S + (size_t)bt * N_ * N_;
    _Float16* stpk = STpk + (size_t)bt * STPK_BT;
    int tid = threadIdx.x;
    int q  = tid & 15, r0  = tid >> 4;   // load mapping
    int q2 = tid & 7,  nr0 = tid >> 3;   // ST-store mapping
    int lane = tid & 63, wv = tid >> 6;  // MFMA mapping
    int l15 = lane & 15, lk = lane >> 4;
    const float* A = x + (size_t)(bt - 1) * F0 * N_;  // valid only when t>0
    f32x4 acc = (f32x4){0.f, 0.f, 0.f, 0.f};

    for (int m0 = 0; m0 < N_; m0 += 128) {
        // register-staged load: all 8 NT loads issued before any LDS write
        f32x4 vbuf[8];
        #pragma unroll
        for (int ii = 0; ii < 8; ++ii) {
            int rr = r0 + ii * 16;
            vbuf[ii] = __builtin_nontemporal_load(
                (const f32x4*)(s + (size_t)(m0 + rr) * N_ + n0 + q * 4));
        }
        #pragma unroll
        for (int ii = 0; ii < 8; ++ii) {
            int rr = r0 + ii * 16;
            tile[q * 4 + 0][rr] = vbuf[ii][0];
            tile[q * 4 + 1][rr] = vbuf[ii][1];
            tile[q * 4 + 2][rr] = vbuf[ii][2];
            tile[q * 4 + 3][rr] = vbuf[ii][3];
        }
        __syncthreads();
        // ST store phase (packed hi/lo)
        #pragma unroll
        for (int nn = nr0; nn < 64; nn += 32) {
            #pragma unroll
            for (int ci = 0; ci < 2; ++ci) {
                int mc = ci * 8 + q2;
                half8 h, l;
                #pragma unroll
                for (int e = 0; e < 8; ++e) {
                    float v = tile[nn][mc * 8 + e];
                    _Float16 hh = (_Float16)v;
                    h[e] = hh;
                    l[e] = (_Float16)(v - (float)hh);
                }
                size_t o = ((size_t)(n0 + nn) * 32 + (m0 >> 3) + mc) * 16;
                *(half8*)(stpk + o) = h;
                *(half8*)(stpk + o + 8) = l;
            }
        }
        // MFMA phase: accumulate U1 fragment for this m-range
        if (t > 0) {
            #pragma unroll
            for (int kkl = 0; kkl < 4; ++kkl) {
                int ml = kkl * 32 + lk * 8;
                half8 ah = {}, al = {};
                if (l15 < F0) {
                    const float* ar = A + (size_t)l15 * N_ + m0 + ml;
                    float4 v0 = *(const float4*)(ar);
                    float4 v1 = *(const float4*)(ar + 4);
                    float vv[8] = {v0.x, v0.y, v0.z, v0.w, v1.x, v1.y, v1.z, v1.w};
                    #pragma unroll
                    for (int c = 0; c < 8; ++c) {
                        _Float16 hh = (_Float16)vv[c];
                        ah[c] = hh;
                        al[c] = (_Float16)(vv[c] - (float)hh);
                    }
                }
                half8 bh, bl;
                const float* tr = &tile[wv * 16 + l15][ml];
                #pragma unroll
                for (int e = 0; e < 8; ++e) {
                    float v = tr[e];
                    _Float16 hh = (_Float16)v;
                    bh[e] = hh;
                    bl[e] = (_Float16)(v - (float)hh);
                }
                acc = __builtin_amdgcn_mfma_f32_16x16x32_f16(ah, bh, acc, 0, 0, 0);
                acc = __builtin_amdgcn_mfma_f32_16x16x32_f16(al, bh, acc, 0, 0, 0);
                acc = __builtin_amdgcn_mfma_f32_16x16x32_f16(ah, bl, acc, 0, 0, 0);
            }
        }
        __syncthreads();
    }
    // U1 writes (zeros when t==0): row-major + col-major hi/lo
    {
        int n = n0 + wv * 16 + l15;
        _Float16* O_h = U1h + (size_t)bt * 16 * N_;
        _Float16* O_l = U1l + (size_t)bt * 16 * N_;
        half4v th, tl;
        #pragma unroll
        for (int r = 0; r < 4; ++r) {
            float v = acc[r];
            _Float16 h = (_Float16)v;
            _Float16 lo = (_Float16)(v - (float)h);
            O_h[(size_t)(lk * 4 + r) * N_ + n] = h;
            O_l[(size_t)(lk * 4 + r) * N_ + n] = lo;
            th[r] = h;
            tl[r] = lo;
        }
        size_t to = ((size_t)bt * N_ + n) * 16 + lk * 4;
        *(half4v*)(U1Th + to) = th;
        *(half4v*)(U1Tl + to) = tl;
    }
}

// ---------------- K0b: x -> xT[bt][n][16] hi/lo (rows 12..15 zero) ----------
__global__ void k_transpose_x(const float* __restrict__ x,
                              _Float16* __restrict__ XTh, _Float16* __restrict__ XTl) {
    int bt = blockIdx.x;
    int n = threadIdx.x;
    const float* xc = x + (size_t)bt * F0 * N_;
    half8 hb[2] = {}, lb[2] = {};
    #pragma unroll
    for (int g = 0; g < F0; ++g) {
        float v = xc[(size_t)g * N_ + n];
        _Float16 hh = (_Float16)v;
        hb[g >> 3][g & 7] = hh;
        lb[g >> 3][g & 7] = (_Float16)(v - (float)hh);
    }
    size_t o = ((size_t)bt * N_ + n) * 16;
    *(half8*)(XTh + o) = hb[0];
    *(half8*)(XTh + o + 8) = hb[1];
    *(half8*)(XTl + o) = lb[0];
    *(half8*)(XTl + o + 8) = lb[1];
}

// ---------------- K2: V1(b,t) = U1(b,t-1) @ S(b,t) -> col-major hi/lo -------
// grid (BT,2), wave=32 cols
__global__ void k_chainV1(const _Float16* __restrict__ Ah, const _Float16* __restrict__ Al,
                          const _Float16* __restrict__ STpk,
                          _Float16* __restrict__ OTh, _Float16* __restrict__ OTl) {
    int bt = blockIdx.x;
    int t = bt & (T_ - 1);
    int wave = threadIdx.x >> 6;
    int lane = threadIdx.x & 63;
    int l15 = lane & 15;
    int lk = lane >> 4;
    int n0 = blockIdx.y * 128 + wave * 32;

    f32x4 acc[2];
    #pragma unroll
    for (int j = 0; j < 2; ++j) acc[j] = (f32x4){0.f, 0.f, 0.f, 0.f};

    if (t > 0) {
        const _Float16* A_h = Ah + (size_t)(bt - 1) * 16 * N_;
        const _Float16* A_l = Al + (size_t)(bt - 1) * 16 * N_;
        const _Float16* Bp = STpk + (size_t)bt * STPK_BT;
        #pragma unroll
        for (int kk = 0; kk < 8; ++kk) {
            int kof = kk * 32 + lk * 8;
            half8 ah = *(const half8*)(A_h + (size_t)l15 * N_ + kof);
            half8 al = *(const half8*)(A_l + (size_t)l15 * N_ + kof);
            #pragma unroll
            for (int j = 0; j < 2; ++j) {
                size_t bb = ((size_t)(n0 + j * 16 + l15) * 32 + kk * 4 + lk) * 16;
                half8 bh = *(const half8*)(Bp + bb);
                half8 bl = *(const half8*)(Bp + bb + 8);
                acc[j] = __builtin_amdgcn_mfma_f32_16x16x32_f16(ah, bh, acc[j], 0, 0, 0);
                acc[j] = __builtin_amdgcn_mfma_f32_16x16x32_f16(al, bh, acc[j], 0, 0, 0);
                acc[j] = __builtin_amdgcn_mfma_f32_16x16x32_f16(ah, bl, acc[j], 0, 0, 0);
            }
        }
    }
    #pragma unroll
    for (int j = 0; j < 2; ++j) {
        half4v th, tl;
        #pragma unroll
        for (int r = 0; r < 4; ++r) {
            float v = acc[j][r];
            _Float16 h = (_Float16)v;
            th[r] = h;
            tl[r] = (_Float16)(v - (float)h);
        }
        size_t to = ((size_t)bt * N_ + n0 + j * 16 + l15) * 16 + lk * 4;
        *(half4v*)(OTh + to) = th;
        *(half4v*)(OTl + to) = tl;
    }
}

// ---------------- K3: y1 = tanh(W1cat @ Zcat + b1) -> Y1T hi/lo -------------
__global__ void k_combine1(const _Float16* __restrict__ XTh, const _Float16* __restrict__ XTl,
                           const _Float16* __restrict__ U1Th, const _Float16* __restrict__ U1Tl,
                           const _Float16* __restrict__ V1Th, const _Float16* __restrict__ V1Tl,
                           const float* __restrict__ W1, const float* __restrict__ b1,
                           _Float16* __restrict__ Y1Th, _Float16* __restrict__ Y1Tl) {
    __shared__ _Float16 wh[64 * 72], wl[64 * 72];
    int bt = blockIdx.x;
    int tid = threadIdx.x;
    for (int i = tid; i < 64 * 72; i += 256) {
        int f = i / 72, k = i % 72;
        float v = 0.f;
        if (k < 12) v = W1[f * 36 + k];
        else if (k >= 16 && k < 28) v = W1[f * 36 + 12 + (k - 16)];
        else if (k >= 32 && k < 44) v = W1[f * 36 + 24 + (k - 32)];
        _Float16 hh = (_Float16)v;
        wh[i] = hh;
        wl[i] = (_Float16)(v - (float)hh);
    }
    __syncthreads();

    int wv = tid >> 6, lane = tid & 63, l15 = lane & 15, lk = lane >> 4;
    int n0 = wv * 64;
    f32x4 acc[4][4];
    #pragma unroll
    for (int i = 0; i < 4; ++i)
        #pragma unroll
        for (int j = 0; j < 4; ++j) acc[i][j] = (f32x4){0.f, 0.f, 0.f, 0.f};

    #pragma unroll
    for (int kk = 0; kk < 2; ++kk) {
        half8 bh[4], bl[4];
        #pragma unroll
        for (int j = 0; j < 4; ++j) {
            size_t base16 = ((size_t)bt * N_ + n0 + j * 16 + l15) * 16;
            if (kk == 0) {
                if (lk < 2) {
                    bh[j] = *(const half8*)(XTh + base16 + lk * 8);
                    bl[j] = *(const half8*)(XTl + base16 + lk * 8);
                } else {
                    bh[j] = *(const half8*)(U1Th + base16 + (lk - 2) * 8);
                    bl[j] = *(const half8*)(U1Tl + base16 + (lk - 2) * 8);
                }
            } else {
                if (lk < 2) {
                    bh[j] = *(const half8*)(V1Th + base16 + lk * 8);
                    bl[j] = *(const half8*)(V1Tl + base16 + lk * 8);
                } else {
                    bh[j] = half8{};
                    bl[j] = half8{};
                }
            }
        }
        #pragma unroll
        for (int i = 0; i < 4; ++i) {
            half8 ah = *(const half8*)(wh + (i * 16 + l15) * 72 + kk * 32 + lk * 8);
            half8 al = *(const half8*)(wl + (i * 16 + l15) * 72 + kk * 32 + lk * 8);
            #pragma unroll
            for (int j = 0; j < 4; ++j) {
                acc[i][j] = __builtin_amdgcn_mfma_f32_16x16x32_f16(ah, bh[j], acc[i][j], 0, 0, 0);
                acc[i][j] = __builtin_amdgcn_mfma_f32_16x16x32_f16(al, bh[j], acc[i][j], 0, 0, 0);
                acc[i][j] = __builtin_amdgcn_mfma_f32_16x16x32_f16(ah, bl[j], acc[i][j], 0, 0, 0);
            }
        }
    }
    #pragma unroll
    for (int i = 0; i < 4; ++i) {
        float bb[4];
        #pragma unroll
        for (int r = 0; r < 4; ++r) bb[r] = b1[i * 16 + lk * 4 + r];
        #pragma unroll
        for (int j = 0; j < 4; ++j) {
            half4v th, tl;
            #pragma unroll
            for (int r = 0; r < 4; ++r) {
                float yv = tanh_fast(acc[i][j][r] + bb[r]);
                _Float16 h = (_Float16)yv;
                th[r] = h;
                tl[r] = (_Float16)(yv - (float)h);
            }
            size_t to = ((size_t)bt * N_ + n0 + j * 16 + l15) * 64 + i * 16 + lk * 4;
            *(half4v*)(Y1Th + to) = th;
            *(half4v*)(Y1Tl + to) = tl;
        }
    }
}

// ---------------- K4: projections G=W2v@Y1, H=W2u@Y1, Y2a=W2y@Y1 ------------
__global__ void k_proj(const _Float16* __restrict__ Y1Th, const _Float16* __restrict__ Y1Tl,
                       const float* __restrict__ W2,
                       _Float16* __restrict__ Gh, _Float16* __restrict__ Gl,
                       float* __restrict__ Hf, float* __restrict__ Y2a) {
    __shared__ _Float16 wh[96 * 72], wl[96 * 72];
    int bt = blockIdx.x;
    int tid = threadIdx.x;
    for (int i = tid; i < 96 * 64; i += 256) {
        int r = i >> 6, g = i & 63;
        int f, off;
        if (r < 32)      { f = r;      off = 128; }   // W2v -> G
        else if (r < 64) { f = r - 32; off = 64;  }   // W2u -> H
        else             { f = r - 64; off = 0;   }   // W2y -> Y2a
        float v = W2[f * 192 + off + g];
        _Float16 hh = (_Float16)v;
        wh[r * 72 + g] = hh;
        wl[r * 72 + g] = (_Float16)(v - (float)hh);
    }
    __syncthreads();

    int wv = tid >> 6, lane = tid & 63, l15 = lane & 15, lk = lane >> 4;
    int n0 = wv * 64;
    f32x4 acc[6][4];
    #pragma unroll
    for (int i = 0; i < 6; ++i)
        #pragma unroll
        for (int j = 0; j < 4; ++j) acc[i][j] = (f32x4){0.f, 0.f, 0.f, 0.f};

    const _Float16* Bh = Y1Th + (size_t)bt * N_ * 64;
    const _Float16* Bl = Y1Tl + (size_t)bt * N_ * 64;
    #pragma unroll
    for (int kk = 0; kk < 2; ++kk) {
        int kof = kk * 32 + lk * 8;
        half8 bh[4], bl[4];
        #pragma unroll
        for (int j = 0; j < 4; ++j) {
            bh[j] = *(const half8*)(Bh + (size_t)(n0 + j * 16 + l15) * 64 + kof);
            bl[j] = *(const half8*)(Bl + (size_t)(n0 + j * 16 + l15) * 64 + kof);
        }
        #pragma unroll
        for (int i = 0; i < 6; ++i) {
            half8 ah = *(const half8*)(wh + (i * 16 + l15) * 72 + kof);
            half8 al = *(const half8*)(wl + (i * 16 + l15) * 72 + kof);
            #pragma unroll
            for (int j = 0; j < 4; ++j) {
                acc[i][j] = __builtin_amdgcn_mfma_f32_16x16x32_f16(ah, bh[j], acc[i][j], 0, 0, 0);
                acc[i][j] = __builtin_amdgcn_mfma_f32_16x16x32_f16(al, bh[j], acc[i][j], 0, 0, 0);
                acc[i][j] = __builtin_amdgcn_mfma_f32_16x16x32_f16(ah, bl[j], acc[i][j], 0, 0, 0);
            }
        }
    }
    #pragma unroll
    for (int i = 0; i < 6; ++i)
        #pragma unroll
        for (int j = 0; j < 4; ++j)
            #pragma unroll
            for (int r = 0; r < 4; ++r) {
                int row = i * 16 + lk * 4 + r;   // 0..95
                int col = n0 + j * 16 + l15;
                float v = acc[i][j][r];
                if (row < 32) {
                    _Float16 hh = (_Float16)v;
                    size_t o = ((size_t)bt * 32 + row) * N_ + col;
                    Gh[o] = hh;
                    Gl[o] = (_Float16)(v - (float)hh);
                } else if (row < 64) {
                    Hf[((size_t)bt * 32 + row - 32) * N_ + col] = v;
                } else {
                    Y2a[((size_t)bt * 32 + row - 64) * N_ + col] = v;
                }
            }
}

// ---------------- K5: R(b,t) = H(b,t) + G(b,t-1)@S(b,t), hi/lo out ----------
// grid (BT,2), wave=32 cols
__global__ void k_chainR(const _Float16* __restrict__ Gh, const _Float16* __restrict__ Gl,
                         const _Float16* __restrict__ STpk,
                         const float* __restrict__ Hf,
                         _Float16* __restrict__ Rh, _Float16* __restrict__ Rl) {
    int bt = blockIdx.x;
    int t = bt & (T_ - 1);
    int wave = threadIdx.x >> 6;
    int lane = threadIdx.x & 63;
    int l15 = lane & 15;
    int lk = lane >> 4;
    int n0 = blockIdx.y * 128 + wave * 32;

    f32x4 acc[2][2];
    #pragma unroll
    for (int i = 0; i < 2; ++i)
        #pragma unroll
        for (int j = 0; j < 2; ++j) acc[i][j] = (f32x4){0.f, 0.f, 0.f, 0.f};

    if (t > 0) {
        const _Float16* A_h = Gh + (size_t)(bt - 1) * 32 * N_;
        const _Float16* A_l = Gl + (size_t)(bt - 1) * 32 * N_;
        const _Float16* Bp = STpk + (size_t)bt * STPK_BT;
        #pragma unroll
        for (int kk = 0; kk < 8; ++kk) {
            int kof = kk * 32 + lk * 8;
            half8 ah[2], al[2];
            #pragma unroll
            for (int i = 0; i < 2; ++i) {
                ah[i] = *(const half8*)(A_h + (size_t)(i * 16 + l15) * N_ + kof);
                al[i] = *(const half8*)(A_l + (size_t)(i * 16 + l15) * N_ + kof);
            }
            #pragma unroll
            for (int j = 0; j < 2; ++j) {
                size_t bb = ((size_t)(n0 + j * 16 + l15) * 32 + kk * 4 + lk) * 16;
                half8 bh = *(const half8*)(Bp + bb);
                half8 bl = *(const half8*)(Bp + bb + 8);
                #pragma unroll
                for (int i = 0; i < 2; ++i) {
                    acc[i][j] = __builtin_amdgcn_mfma_f32_16x16x32_f16(ah[i], bh, acc[i][j], 0, 0, 0);
                    acc[i][j] = __builtin_amdgcn_mfma_f32_16x16x32_f16(al[i], bh, acc[i][j], 0, 0, 0);
                    acc[i][j] = __builtin_amdgcn_mfma_f32_16x16x32_f16(ah[i], bl, acc[i][j], 0, 0, 0);
                }
            }
        }
    }
    const float* Hb = Hf + (size_t)bt * 32 * N_;
    _Float16* R_h = Rh + (size_t)bt * 32 * N_;
    _Float16* R_l = Rl + (size_t)bt * 32 * N_;
    #pragma unroll
    for (int i = 0; i < 2; ++i)
        #pragma unroll
        for (int j = 0; j < 2; ++j)
            #pragma unroll
            for (int r = 0; r < 4; ++r) {
                size_t idx = (size_t)(i * 16 + lk * 4 + r) * N_ + n0 + j * 16 + l15;
                float v = acc[i][j][r] + Hb[idx];
                _Float16 h = (_Float16)v;
                R_h[idx] = h;
                R_l[idx] = (_Float16)(v - (float)h);
            }
}

// ---------------- K6: y2 = tanh(b2 + Y2a + R(t-1)@S(t)); readout -> out -----
// grid (BT,2)
__global__ void k_chainY2(const _Float16* __restrict__ Rh, const _Float16* __restrict__ Rl,
                          const _Float16* __restrict__ STpk,
                          const float* __restrict__ Y2a, const float* __restrict__ b2,
                          const float* __restrict__ A1, const float* __restrict__ c1,
                          const float* __restrict__ A2, const float* __restrict__ c2,
                          float* __restrict__ out) {
    __shared__ float y2s[32 * 133];   // 17 KB, pad 133 -> conflict-free
    __shared__ float la1[32 * 33];
    int bt = blockIdx.x;
    int t = bt & (T_ - 1);
    int tid = threadIdx.x;
    for (int i = tid; i < 32 * 32; i += 256) la1[(i >> 5) * 33 + (i & 31)] = A1[i];

    int wave = tid >> 6;
    int lane = tid & 63;
    int l15 = lane & 15;
    int lk = lane >> 4;
    int n0 = blockIdx.y * 128 + wave * 32;

    f32x4 acc[2][2];
    #pragma unroll
    for (int i = 0; i < 2; ++i)
        #pragma unroll
        for (int j = 0; j < 2; ++j) acc[i][j] = (f32x4){0.f, 0.f, 0.f, 0.f};

    if (t > 0) {
        const _Float16* A_h = Rh + (size_t)(bt - 1) * 32 * N_;
        const _Float16* A_l = Rl + (size_t)(bt - 1) * 32 * N_;
        const _Float16* Bp = STpk + (size_t)bt * STPK_BT;
        #pragma unroll
        for (int kk = 0; kk < 8; ++kk) {
            int kof = kk * 32 + lk * 8;
            half8 ah[2], al[2];
            #pragma unroll
            for (int i = 0; i < 2; ++i) {
                ah[i] = *(const half8*)(A_h + (size_t)(i * 16 + l15) * N_ + kof);
                al[i] = *(const half8*)(A_l + (size_t)(i * 16 + l15) * N_ + kof);
            }
            #pragma unroll
            for (int j = 0; j < 2; ++j) {
                size_t bb = ((size_t)(n0 + j * 16 + l15) * 32 + kk * 4 + lk) * 16;
                half8 bh = *(const half8*)(Bp + bb);
                half8 bl = *(const half8*)(Bp + bb + 8);
                #pragma unroll
                for (int i = 0; i < 2; ++i) {
                    acc[i][j] = __builtin_amdgcn_mfma_f32_16x16x32_f16(ah[i], bh, acc[i][j], 0, 0, 0);
                    acc[i][j] = __builtin_amdgcn_mfma_f32_16x16x32_f16(al[i], bh, acc[i][j], 0, 0, 0);
                    acc[i][j] = __builtin_amdgcn_mfma_f32_16x16x32_f16(ah[i], bl, acc[i][j], 0, 0, 0);
                }
            }
        }
    }
    const float* Ya = Y2a + (size_t)bt * 32 * N_;
    int colb0 = wave * 32;
    #pragma unroll
    for (int i = 0; i < 2; ++i)
        #pragma unroll
        for (int j = 0; j < 2; ++j)
            #pragma unroll
            for (int r = 0; r < 4; ++r) {
                int row = i * 16 + lk * 4 + r;
                int colb = colb0 + j * 16 + l15;
                int n = blockIdx.y * 128 + colb;
                y2s[row * 133 + colb] = acc[i][j][r] + Ya[(size_t)row * N_ + n] + b2[row];
            }
    __syncthreads();

    if (tid < 128) {
        int colb = tid;
        int n = blockIdx.y * 128 + colb;
        float y2v[32];
        #pragma unroll
        for (int f = 0; f < 32; ++f) y2v[f] = tanh_fast(y2s[f * 133 + colb]);
        float o0 = 0.f, o1 = 0.f;
        #pragma unroll
        for (int j = 0; j < 32; ++j) {
            const float* a1r = la1 + j * 33;
            float s = c1[j];
            #pragma unroll
            for (int f = 0; f < 32; ++f) s += a1r[f] * y2v[f];
            float hj = tanh_fast(s);
            o0 += A2[j] * hj;
            o1 += A2[32 + j] * hj;
        }
        out[((size_t)bt * 2 + 0) * N_ + n] = o0 + c2[0];
        out[((size_t)bt * 2 + 1) * N_ + n] = o1 + c2[1];
    }
}

extern "C" void kernel_launch(void* const* d_in, const int* in_sizes, int n_in,
                              void* d_out, int out_size, void* d_ws, size_t ws_size,
                              hipStream_t stream) {
    const float* x  = (const float*)d_in[0];
    const float* S  = (const float*)d_in[1];
    const float* W1 = (const float*)d_in[2];
    const float* b1 = (const float*)d_in[3];
    const float* W2 = (const float*)d_in[4];
    const float* b2 = (const float*)d_in[5];
    const float* A1 = (const float*)d_in[6];
    const float* c1 = (const float*)d_in[7];
    const float* A2 = (const float*)d_in[8];
    const float* c2 = (const float*)d_in[9];
    float* out = (float*)d_out;

    char* ws = (char*)d_ws;
    const size_t SZ_STPK = (size_t)BT_ * STPK_BT * 2;  // 134,217,728 (hi+lo packed)
    const size_t SZ_Y1T = (size_t)BT_ * N_ * 64 * 2;   // 16,777,216 per plane
    const size_t SZ_G   = (size_t)BT_ * 32 * N_ * 2;   //  8,388,608 per plane
    const size_t SZ_H   = (size_t)BT_ * 32 * N_ * 4;   // 16,777,216 (f32)
    const size_t SZ_T16 = (size_t)BT_ * N_ * 16 * 2;   //  4,194,304 (16-row plane)
    size_t off = 0;
    _Float16* STpk = (_Float16*)(ws + off); off += SZ_STPK;
    _Float16* Y1Th = (_Float16*)(ws + off); off += SZ_Y1T;
    _Float16* Y1Tl = (_Float16*)(ws + off); off += SZ_Y1T;
    _Float16* Gh   = (_Float16*)(ws + off); off += SZ_G;
    _Float16* Gl   = (_Float16*)(ws + off); off += SZ_G;
    float*    Hf   = (float*)(ws + off); off += SZ_H;
    float*    Y2a  = (float*)(ws + off); off += SZ_H;
    _Float16* Rh   = (_Float16*)(ws + off); off += SZ_G;
    _Float16* Rl   = (_Float16*)(ws + off); off += SZ_G;
    if (ws_size < off) return;  // insufficient scratch -> clean failure

    // overlays (lifetime-disjoint):
    //   XT  (written K0b, read K3)  lives in Hf  region (Hf written later by k_proj)
    //   U1T (written K0,  read K3)  lives in Y2a region first half
    //   V1T (written K2,  read K3)  lives in Y2a region second half
    //   U1 row-major (written K0, read K2) lives in R region (R written by k_chainR)
    _Float16* XTh  = (_Float16*)Hf;
    _Float16* XTl  = XTh + SZ_T16 / 2;
    _Float16* U1Th = (_Float16*)Y2a;
    _Float16* U1Tl = U1Th + SZ_T16 / 2;
    _Float16* V1Th = U1Tl + SZ_T16 / 2;
    _Float16* V1Tl = V1Th + SZ_T16 / 2;
    _Float16* U1h  = Rh;
    _Float16* U1l  = Rl;

    k_transpose_u1<<<dim3(BT_, 4), 256, 0, stream>>>(S, x, STpk,
                                                     U1h, U1l, U1Th, U1Tl);
    k_transpose_x<<<BT_, 256, 0, stream>>>(x, XTh, XTl);
    k_chainV1<<<dim3(BT_, 2), 256, 0, stream>>>(U1h, U1l, STpk, V1Th, V1Tl);
    k_combine1<<<BT_, 256, 0, stream>>>(XTh, XTl, U1Th, U1Tl, V1Th, V1Tl, W1, b1, Y1Th, Y1Tl);
    k_proj<<<BT_, 256, 0, stream>>>(Y1Th, Y1Tl, W2, Gh, Gl, Hf, Y2a);
    k_chainR<<<dim3(BT_, 2), 256, 0, stream>>>(Gh, Gl, STpk, Hf, Rh, Rl);
    k_chainY2<<<dim3(BT_, 2), 256, 0, stream>>>(Rh, Rl, STpk, Y2a, b2,
                                                A1, c1, A2, c2, out);
}

// Round 17
// 198.381 us; speedup vs baseline: 1.1516x; 1.1516x over previous
//
#include <hip/hip_runtime.h>
#include <hip/hip_fp16.h>

typedef _Float16 half8 __attribute__((ext_vector_type(8)));
typedef _Float16 half4v __attribute__((ext_vector_type(4)));
typedef float f32x4 __attribute__((ext_vector_type(4)));

static constexpr int B_ = 8, T_ = 64, N_ = 256;
static constexpr int F0 = 12, F1 = 64, F2 = 32;
static constexpr int BT_ = B_ * T_;

__device__ inline float tanh_fast(float x) {
    x = fminf(20.f, fmaxf(-20.f, x));
    float e = __expf(2.f * x);
    return (e - 1.f) / (e + 1.f);
}

// ---------------- K0: U1(b,t) = x(b,t-1) @ S(b,t) via LDS-transposed S ------
// grid (BT,4): block owns 64 cols (n), 2 m-tiles of 128. Plain loads warm L3.
__global__ __launch_bounds__(256) void k_u1(
    const float* __restrict__ S, const float* __restrict__ x,
    _Float16* __restrict__ U1h, _Float16* __restrict__ U1l,
    _Float16* __restrict__ U1Th, _Float16* __restrict__ U1Tl) {
    __shared__ float tile[64][129];   // 33 KB
    int bt = blockIdx.x;
    int t  = bt & (T_ - 1);
    int n0 = blockIdx.y * 64;
    const float* s = S + (size_t)bt * N_ * N_;
    int tid = threadIdx.x;
    int q  = tid & 15, r0  = tid >> 4;   // load mapping
    int lane = tid & 63, wv = tid >> 6;  // MFMA mapping
    int l15 = lane & 15, lk = lane >> 4;
    const float* A = x + (size_t)(bt - 1) * F0 * N_;  // valid only when t>0
    f32x4 acc = (f32x4){0.f, 0.f, 0.f, 0.f};

    for (int m0 = 0; m0 < N_; m0 += 128) {
        f32x4 vbuf[8];
        #pragma unroll
        for (int ii = 0; ii < 8; ++ii) {
            int rr = r0 + ii * 16;
            vbuf[ii] = *(const f32x4*)(s + (size_t)(m0 + rr) * N_ + n0 + q * 4);
        }
        #pragma unroll
        for (int ii = 0; ii < 8; ++ii) {
            int rr = r0 + ii * 16;
            tile[q * 4 + 0][rr] = vbuf[ii][0];
            tile[q * 4 + 1][rr] = vbuf[ii][1];
            tile[q * 4 + 2][rr] = vbuf[ii][2];
            tile[q * 4 + 3][rr] = vbuf[ii][3];
        }
        __syncthreads();
        if (t > 0) {
            #pragma unroll
            for (int kkl = 0; kkl < 4; ++kkl) {
                int ml = kkl * 32 + lk * 8;
                half8 ah = {}, al = {};
                if (l15 < F0) {
                    const float* ar = A + (size_t)l15 * N_ + m0 + ml;
                    float4 v0 = *(const float4*)(ar);
                    float4 v1 = *(const float4*)(ar + 4);
                    float vv[8] = {v0.x, v0.y, v0.z, v0.w, v1.x, v1.y, v1.z, v1.w};
                    #pragma unroll
                    for (int c = 0; c < 8; ++c) {
                        _Float16 hh = (_Float16)vv[c];
                        ah[c] = hh;
                        al[c] = (_Float16)(vv[c] - (float)hh);
                    }
                }
                half8 bh, bl;
                const float* tr = &tile[wv * 16 + l15][ml];
                #pragma unroll
                for (int e = 0; e < 8; ++e) {
                    float v = tr[e];
                    _Float16 hh = (_Float16)v;
                    bh[e] = hh;
                    bl[e] = (_Float16)(v - (float)hh);
                }
                acc = __builtin_amdgcn_mfma_f32_16x16x32_f16(ah, bh, acc, 0, 0, 0);
                acc = __builtin_amdgcn_mfma_f32_16x16x32_f16(al, bh, acc, 0, 0, 0);
                acc = __builtin_amdgcn_mfma_f32_16x16x32_f16(ah, bl, acc, 0, 0, 0);
            }
        }
        __syncthreads();
    }
    {
        int n = n0 + wv * 16 + l15;
        _Float16* O_h = U1h + (size_t)bt * 16 * N_;
        _Float16* O_l = U1l + (size_t)bt * 16 * N_;
        half4v th, tl;
        #pragma unroll
        for (int r = 0; r < 4; ++r) {
            float v = acc[r];
            _Float16 h = (_Float16)v;
            _Float16 lo = (_Float16)(v - (float)h);
            O_h[(size_t)(lk * 4 + r) * N_ + n] = h;
            O_l[(size_t)(lk * 4 + r) * N_ + n] = lo;
            th[r] = h;
            tl[r] = lo;
        }
        size_t to = ((size_t)bt * N_ + n) * 16 + lk * 4;
        *(half4v*)(U1Th + to) = th;
        *(half4v*)(U1Tl + to) = tl;
    }
}

// ---------------- K0b: x -> xT[bt][n][16] hi/lo (rows 12..15 zero) ----------
__global__ void k_transpose_x(const float* __restrict__ x,
                              _Float16* __restrict__ XTh, _Float16* __restrict__ XTl) {
    int bt = blockIdx.x;
    int n = threadIdx.x;
    const float* xc = x + (size_t)bt * F0 * N_;
    half8 hb[2] = {}, lb[2] = {};
    #pragma unroll
    for (int g = 0; g < F0; ++g) {
        float v = xc[(size_t)g * N_ + n];
        _Float16 hh = (_Float16)v;
        hb[g >> 3][g & 7] = hh;
        lb[g >> 3][g & 7] = (_Float16)(v - (float)hh);
    }
    size_t o = ((size_t)bt * N_ + n) * 16;
    *(half8*)(XTh + o) = hb[0];
    *(half8*)(XTh + o + 8) = hb[1];
    *(half8*)(XTl + o) = lb[0];
    *(half8*)(XTl + o + 8) = lb[1];
}

// ---------------- K2: V1(b,t) = U1(b,t-1) @ S(b,t) -> col-major hi/lo -------
// grid (BT,2), wave=32 cols; B built from LDS-transposed S chunks.
__global__ void k_chainV1(const _Float16* __restrict__ Ah, const _Float16* __restrict__ Al,
                          const float* __restrict__ S,
                          _Float16* __restrict__ OTh, _Float16* __restrict__ OTl) {
    __shared__ float tile[128][65];   // 33.3 KB
    int bt = blockIdx.x;
    int t = bt & (T_ - 1);
    int tid = threadIdx.x;
    int nq = tid & 31, mr = tid >> 5;    // load mapping
    int wave = tid >> 6, lane = tid & 63;
    int l15 = lane & 15, lk = lane >> 4;
    int nb0 = blockIdx.y * 128;
    int n0 = nb0 + wave * 32;

    f32x4 acc[2];
    #pragma unroll
    for (int j = 0; j < 2; ++j) acc[j] = (f32x4){0.f, 0.f, 0.f, 0.f};

    if (t > 0) {
        const _Float16* A_h = Ah + (size_t)(bt - 1) * 16 * N_;
        const _Float16* A_l = Al + (size_t)(bt - 1) * 16 * N_;
        const float* Sb = S + (size_t)bt * N_ * N_;
        for (int mc = 0; mc < 4; ++mc) {
            int m0 = mc * 64;
            #pragma unroll
            for (int ii = 0; ii < 8; ++ii) {
                int rr = mr + ii * 8;
                f32x4 v = *(const f32x4*)(Sb + (size_t)(m0 + rr) * N_ + nb0 + nq * 4);
                tile[nq * 4 + 0][rr] = v[0];
                tile[nq * 4 + 1][rr] = v[1];
                tile[nq * 4 + 2][rr] = v[2];
                tile[nq * 4 + 3][rr] = v[3];
            }
            __syncthreads();
            #pragma unroll
            for (int kk = 0; kk < 2; ++kk) {
                int kof = m0 + kk * 32 + lk * 8;
                half8 ah = *(const half8*)(A_h + (size_t)l15 * N_ + kof);
                half8 al = *(const half8*)(A_l + (size_t)l15 * N_ + kof);
                #pragma unroll
                for (int j = 0; j < 2; ++j) {
                    const float* tr = &tile[wave * 32 + j * 16 + l15][kk * 32 + lk * 8];
                    half8 bh, bl;
                    #pragma unroll
                    for (int e = 0; e < 8; ++e) {
                        float v = tr[e];
                        _Float16 hh = (_Float16)v;
                        bh[e] = hh;
                        bl[e] = (_Float16)(v - (float)hh);
                    }
                    acc[j] = __builtin_amdgcn_mfma_f32_16x16x32_f16(ah, bh, acc[j], 0, 0, 0);
                    acc[j] = __builtin_amdgcn_mfma_f32_16x16x32_f16(al, bh, acc[j], 0, 0, 0);
                    acc[j] = __builtin_amdgcn_mfma_f32_16x16x32_f16(ah, bl, acc[j], 0, 0, 0);
                }
            }
            __syncthreads();
        }
    }
    #pragma unroll
    for (int j = 0; j < 2; ++j) {
        half4v th, tl;
        #pragma unroll
        for (int r = 0; r < 4; ++r) {
            float v = acc[j][r];
            _Float16 h = (_Float16)v;
            th[r] = h;
            tl[r] = (_Float16)(v - (float)h);
        }
        size_t to = ((size_t)bt * N_ + n0 + j * 16 + l15) * 16 + lk * 4;
        *(half4v*)(OTh + to) = th;
        *(half4v*)(OTl + to) = tl;
    }
}

// ---------------- K3: y1 = tanh(W1cat @ Zcat + b1) -> Y1T hi/lo -------------
__global__ void k_combine1(const _Float16* __restrict__ XTh, const _Float16* __restrict__ XTl,
                           const _Float16* __restrict__ U1Th, const _Float16* __restrict__ U1Tl,
                           const _Float16* __restrict__ V1Th, const _Float16* __restrict__ V1Tl,
                           const float* __restrict__ W1, const float* __restrict__ b1,
                           _Float16* __restrict__ Y1Th, _Float16* __restrict__ Y1Tl) {
    __shared__ _Float16 wh[64 * 72], wl[64 * 72];
    int bt = blockIdx.x;
    int tid = threadIdx.x;
    for (int i = tid; i < 64 * 72; i += 256) {
        int f = i / 72, k = i % 72;
        float v = 0.f;
        if (k < 12) v = W1[f * 36 + k];
        else if (k >= 16 && k < 28) v = W1[f * 36 + 12 + (k - 16)];
        else if (k >= 32 && k < 44) v = W1[f * 36 + 24 + (k - 32)];
        _Float16 hh = (_Float16)v;
        wh[i] = hh;
        wl[i] = (_Float16)(v - (float)hh);
    }
    __syncthreads();

    int wv = tid >> 6, lane = tid & 63, l15 = lane & 15, lk = lane >> 4;
    int n0 = wv * 64;
    f32x4 acc[4][4];
    #pragma unroll
    for (int i = 0; i < 4; ++i)
        #pragma unroll
        for (int j = 0; j < 4; ++j) acc[i][j] = (f32x4){0.f, 0.f, 0.f, 0.f};

    #pragma unroll
    for (int kk = 0; kk < 2; ++kk) {
        half8 bh[4], bl[4];
        #pragma unroll
        for (int j = 0; j < 4; ++j) {
            size_t base16 = ((size_t)bt * N_ + n0 + j * 16 + l15) * 16;
            if (kk == 0) {
                if (lk < 2) {
                    bh[j] = *(const half8*)(XTh + base16 + lk * 8);
                    bl[j] = *(const half8*)(XTl + base16 + lk * 8);
                } else {
                    bh[j] = *(const half8*)(U1Th + base16 + (lk - 2) * 8);
                    bl[j] = *(const half8*)(U1Tl + base16 + (lk - 2) * 8);
                }
            } else {
                if (lk < 2) {
                    bh[j] = *(const half8*)(V1Th + base16 + lk * 8);
                    bl[j] = *(const half8*)(V1Tl + base16 + lk * 8);
                } else {
                    bh[j] = half8{};
                    bl[j] = half8{};
                }
            }
        }
        #pragma unroll
        for (int i = 0; i < 4; ++i) {
            half8 ah = *(const half8*)(wh + (i * 16 + l15) * 72 + kk * 32 + lk * 8);
            half8 al = *(const half8*)(wl + (i * 16 + l15) * 72 + kk * 32 + lk * 8);
            #pragma unroll
            for (int j = 0; j < 4; ++j) {
                acc[i][j] = __builtin_amdgcn_mfma_f32_16x16x32_f16(ah, bh[j], acc[i][j], 0, 0, 0);
                acc[i][j] = __builtin_amdgcn_mfma_f32_16x16x32_f16(al, bh[j], acc[i][j], 0, 0, 0);
                acc[i][j] = __builtin_amdgcn_mfma_f32_16x16x32_f16(ah, bl[j], acc[i][j], 0, 0, 0);
            }
        }
    }
    #pragma unroll
    for (int i = 0; i < 4; ++i) {
        float bb[4];
        #pragma unroll
        for (int r = 0; r < 4; ++r) bb[r] = b1[i * 16 + lk * 4 + r];
        #pragma unroll
        for (int j = 0; j < 4; ++j) {
            half4v th, tl;
            #pragma unroll
            for (int r = 0; r < 4; ++r) {
                float yv = tanh_fast(acc[i][j][r] + bb[r]);
                _Float16 h = (_Float16)yv;
                th[r] = h;
                tl[r] = (_Float16)(yv - (float)h);
            }
            size_t to = ((size_t)bt * N_ + n0 + j * 16 + l15) * 64 + i * 16 + lk * 4;
            *(half4v*)(Y1Th + to) = th;
            *(half4v*)(Y1Tl + to) = tl;
        }
    }
}

// ---------------- K4: projections G=W2v@Y1, H=W2u@Y1, Y2a=W2y@Y1 ------------
__global__ void k_proj(const _Float16* __restrict__ Y1Th, const _Float16* __restrict__ Y1Tl,
                       const float* __restrict__ W2,
                       _Float16* __restrict__ Gh, _Float16* __restrict__ Gl,
                       float* __restrict__ Hf, float* __restrict__ Y2a) {
    __shared__ _Float16 wh[96 * 72], wl[96 * 72];
    int bt = blockIdx.x;
    int tid = threadIdx.x;
    for (int i = tid; i < 96 * 64; i += 256) {
        int r = i >> 6, g = i & 63;
        int f, off;
        if (r < 32)      { f = r;      off = 128; }   // W2v -> G
        else if (r < 64) { f = r - 32; off = 64;  }   // W2u -> H
        else             { f = r - 64; off = 0;   }   // W2y -> Y2a
        float v = W2[f * 192 + off + g];
        _Float16 hh = (_Float16)v;
        wh[r * 72 + g] = hh;
        wl[r * 72 + g] = (_Float16)(v - (float)hh);
    }
    __syncthreads();

    int wv = tid >> 6, lane = tid & 63, l15 = lane & 15, lk = lane >> 4;
    int n0 = wv * 64;
    f32x4 acc[6][4];
    #pragma unroll
    for (int i = 0; i < 6; ++i)
        #pragma unroll
        for (int j = 0; j < 4; ++j) acc[i][j] = (f32x4){0.f, 0.f, 0.f, 0.f};

    const _Float16* Bh = Y1Th + (size_t)bt * N_ * 64;
    const _Float16* Bl = Y1Tl + (size_t)bt * N_ * 64;
    #pragma unroll
    for (int kk = 0; kk < 2; ++kk) {
        int kof = kk * 32 + lk * 8;
        half8 bh[4], bl[4];
        #pragma unroll
        for (int j = 0; j < 4; ++j) {
            bh[j] = *(const half8*)(Bh + (size_t)(n0 + j * 16 + l15) * 64 + kof);
            bl[j] = *(const half8*)(Bl + (size_t)(n0 + j * 16 + l15) * 64 + kof);
        }
        #pragma unroll
        for (int i = 0; i < 6; ++i) {
            half8 ah = *(const half8*)(wh + (i * 16 + l15) * 72 + kof);
            half8 al = *(const half8*)(wl + (i * 16 + l15) * 72 + kof);
            #pragma unroll
            for (int j = 0; j < 4; ++j) {
                acc[i][j] = __builtin_amdgcn_mfma_f32_16x16x32_f16(ah, bh[j], acc[i][j], 0, 0, 0);
                acc[i][j] = __builtin_amdgcn_mfma_f32_16x16x32_f16(al, bh[j], acc[i][j], 0, 0, 0);
                acc[i][j] = __builtin_amdgcn_mfma_f32_16x16x32_f16(ah, bl[j], acc[i][j], 0, 0, 0);
            }
        }
    }
    #pragma unroll
    for (int i = 0; i < 6; ++i)
        #pragma unroll
        for (int j = 0; j < 4; ++j)
            #pragma unroll
            for (int r = 0; r < 4; ++r) {
                int row = i * 16 + lk * 4 + r;   // 0..95
                int col = n0 + j * 16 + l15;
                float v = acc[i][j][r];
                if (row < 32) {
                    _Float16 hh = (_Float16)v;
                    size_t o = ((size_t)bt * 32 + row) * N_ + col;
                    Gh[o] = hh;
                    Gl[o] = (_Float16)(v - (float)hh);
                } else if (row < 64) {
                    Hf[((size_t)bt * 32 + row - 32) * N_ + col] = v;
                } else {
                    Y2a[((size_t)bt * 32 + row - 64) * N_ + col] = v;
                }
            }
}

// ---------------- K5: R(b,t) = H(b,t) + G(b,t-1)@S(b,t), hi/lo out ----------
// grid (BT,2), wave=32 cols; B from LDS-transposed S.
__global__ void k_chainR(const _Float16* __restrict__ Gh, const _Float16* __restrict__ Gl,
                         const float* __restrict__ S,
                         const float* __restrict__ Hf,
                         _Float16* __restrict__ Rh, _Float16* __restrict__ Rl) {
    __shared__ float tile[128][65];
    int bt = blockIdx.x;
    int t = bt & (T_ - 1);
    int tid = threadIdx.x;
    int nq = tid & 31, mr = tid >> 5;
    int wave = tid >> 6, lane = tid & 63;
    int l15 = lane & 15, lk = lane >> 4;
    int nb0 = blockIdx.y * 128;
    int n0 = nb0 + wave * 32;

    f32x4 acc[2][2];
    #pragma unroll
    for (int i = 0; i < 2; ++i)
        #pragma unroll
        for (int j = 0; j < 2; ++j) acc[i][j] = (f32x4){0.f, 0.f, 0.f, 0.f};

    if (t > 0) {
        const _Float16* A_h = Gh + (size_t)(bt - 1) * 32 * N_;
        const _Float16* A_l = Gl + (size_t)(bt - 1) * 32 * N_;
        const float* Sb = S + (size_t)bt * N_ * N_;
        for (int mc = 0; mc < 4; ++mc) {
            int m0 = mc * 64;
            #pragma unroll
            for (int ii = 0; ii < 8; ++ii) {
                int rr = mr + ii * 8;
                f32x4 v = *(const f32x4*)(Sb + (size_t)(m0 + rr) * N_ + nb0 + nq * 4);
                tile[nq * 4 + 0][rr] = v[0];
                tile[nq * 4 + 1][rr] = v[1];
                tile[nq * 4 + 2][rr] = v[2];
                tile[nq * 4 + 3][rr] = v[3];
            }
            __syncthreads();
            #pragma unroll
            for (int kk = 0; kk < 2; ++kk) {
                int kof = m0 + kk * 32 + lk * 8;
                half8 ah[2], al[2];
                #pragma unroll
                for (int i = 0; i < 2; ++i) {
                    ah[i] = *(const half8*)(A_h + (size_t)(i * 16 + l15) * N_ + kof);
                    al[i] = *(const half8*)(A_l + (size_t)(i * 16 + l15) * N_ + kof);
                }
                #pragma unroll
                for (int j = 0; j < 2; ++j) {
                    const float* tr = &tile[wave * 32 + j * 16 + l15][kk * 32 + lk * 8];
                    half8 bh, bl;
                    #pragma unroll
                    for (int e = 0; e < 8; ++e) {
                        float v = tr[e];
                        _Float16 hh = (_Float16)v;
                        bh[e] = hh;
                        bl[e] = (_Float16)(v - (float)hh);
                    }
                    #pragma unroll
                    for (int i = 0; i < 2; ++i) {
                        acc[i][j] = __builtin_amdgcn_mfma_f32_16x16x32_f16(ah[i], bh, acc[i][j], 0, 0, 0);
                        acc[i][j] = __builtin_amdgcn_mfma_f32_16x16x32_f16(al[i], bh, acc[i][j], 0, 0, 0);
                        acc[i][j] = __builtin_amdgcn_mfma_f32_16x16x32_f16(ah[i], bl, acc[i][j], 0, 0, 0);
                    }
                }
            }
            __syncthreads();
        }
    }
    const float* Hb = Hf + (size_t)bt * 32 * N_;
    _Float16* R_h = Rh + (size_t)bt * 32 * N_;
    _Float16* R_l = Rl + (size_t)bt * 32 * N_;
    #pragma unroll
    for (int i = 0; i < 2; ++i)
        #pragma unroll
        for (int j = 0; j < 2; ++j)
            #pragma unroll
            for (int r = 0; r < 4; ++r) {
                size_t idx = (size_t)(i * 16 + lk * 4 + r) * N_ + n0 + j * 16 + l15;
                float v = acc[i][j][r] + Hb[idx];
                _Float16 h = (_Float16)v;
                R_h[idx] = h;
                R_l[idx] = (_Float16)(v - (float)h);
            }
}

// ---------------- K6: y2 = tanh(b2 + Y2a + R(t-1)@S(t)); readout -> out -----
// grid (BT,2); B from LDS-transposed S.
__global__ void k_chainY2(const _Float16* __restrict__ Rh, const _Float16* __restrict__ Rl,
                          const float* __restrict__ S,
                          const float* __restrict__ Y2a, const float* __restrict__ b2,
                          const float* __restrict__ A1, const float* __restrict__ c1,
                          const float* __restrict__ A2, const float* __restrict__ c2,
                          float* __restrict__ out) {
    __shared__ float tile[128][65];   // 33.3 KB (reused as y2s after barrier)
    __shared__ float la1[32 * 33];
    int bt = blockIdx.x;
    int t = bt & (T_ - 1);
    int tid = threadIdx.x;
    for (int i = tid; i < 32 * 32; i += 256) la1[(i >> 5) * 33 + (i & 31)] = A1[i];

    int nq = tid & 31, mr = tid >> 5;
    int wave = tid >> 6, lane = tid & 63;
    int l15 = lane & 15, lk = lane >> 4;
    int nb0 = blockIdx.y * 128;
    int n0 = nb0 + wave * 32;

    f32x4 acc[2][2];
    #pragma unroll
    for (int i = 0; i < 2; ++i)
        #pragma unroll
        for (int j = 0; j < 2; ++j) acc[i][j] = (f32x4){0.f, 0.f, 0.f, 0.f};

    if (t > 0) {
        const _Float16* A_h = Rh + (size_t)(bt - 1) * 32 * N_;
        const _Float16* A_l = Rl + (size_t)(bt - 1) * 32 * N_;
        const float* Sb = S + (size_t)bt * N_ * N_;
        for (int mc = 0; mc < 4; ++mc) {
            int m0 = mc * 64;
            #pragma unroll
            for (int ii = 0; ii < 8; ++ii) {
                int rr = mr + ii * 8;
                f32x4 v = *(const f32x4*)(Sb + (size_t)(m0 + rr) * N_ + nb0 + nq * 4);
                tile[nq * 4 + 0][rr] = v[0];
                tile[nq * 4 + 1][rr] = v[1];
                tile[nq * 4 + 2][rr] = v[2];
                tile[nq * 4 + 3][rr] = v[3];
            }
            __syncthreads();
            #pragma unroll
            for (int kk = 0; kk < 2; ++kk) {
                int kof = m0 + kk * 32 + lk * 8;
                half8 ah[2], al[2];
                #pragma unroll
                for (int i = 0; i < 2; ++i) {
                    ah[i] = *(const half8*)(A_h + (size_t)(i * 16 + l15) * N_ + kof);
                    al[i] = *(const half8*)(A_l + (size_t)(i * 16 + l15) * N_ + kof);
                }
                #pragma unroll
                for (int j = 0; j < 2; ++j) {
                    const float* tr = &tile[wave * 32 + j * 16 + l15][kk * 32 + lk * 8];
                    half8 bh, bl;
                    #pragma unroll
                    for (int e = 0; e < 8; ++e) {
                        float v = tr[e];
                        _Float16 hh = (_Float16)v;
                        bh[e] = hh;
                        bl[e] = (_Float16)(v - (float)hh);
                    }
                    #pragma unroll
                    for (int i = 0; i < 2; ++i) {
                        acc[i][j] = __builtin_amdgcn_mfma_f32_16x16x32_f16(ah[i], bh, acc[i][j], 0, 0, 0);
                        acc[i][j] = __builtin_amdgcn_mfma_f32_16x16x32_f16(al[i], bh, acc[i][j], 0, 0, 0);
                        acc[i][j] = __builtin_amdgcn_mfma_f32_16x16x32_f16(ah[i], bl, acc[i][j], 0, 0, 0);
                    }
                }
            }
            __syncthreads();
        }
    }
    // reuse tile as y2s (stride 133; needs 32*133=4256 of 8320 floats)
    float* y2s = &tile[0][0];
    const float* Ya = Y2a + (size_t)bt * 32 * N_;
    int colb0 = wave * 32;
    __syncthreads();
    #pragma unroll
    for (int i = 0; i < 2; ++i)
        #pragma unroll
        for (int j = 0; j < 2; ++j)
            #pragma unroll
            for (int r = 0; r < 4; ++r) {
                int row = i * 16 + lk * 4 + r;
                int colb = colb0 + j * 16 + l15;
                int n = nb0 + colb;
                y2s[row * 133 + colb] = acc[i][j][r] + Ya[(size_t)row * N_ + n] + b2[row];
            }
    __syncthreads();

    if (tid < 128) {
        int colb = tid;
        int n = nb0 + colb;
        float y2v[32];
        #pragma unroll
        for (int f = 0; f < 32; ++f) y2v[f] = tanh_fast(y2s[f * 133 + colb]);
        float o0 = 0.f, o1 = 0.f;
        #pragma unroll
        for (int j = 0; j < 32; ++j) {
            const float* a1r = la1 + j * 33;
            float s = c1[j];
            #pragma unroll
            for (int f = 0; f < 32; ++f) s += a1r[f] * y2v[f];
            float hj = tanh_fast(s);
            o0 += A2[j] * hj;
            o1 += A2[32 + j] * hj;
        }
        out[((size_t)bt * 2 + 0) * N_ + n] = o0 + c2[0];
        out[((size_t)bt * 2 + 1) * N_ + n] = o1 + c2[1];
    }
}

extern "C" void kernel_launch(void* const* d_in, const int* in_sizes, int n_in,
                              void* d_out, int out_size, void* d_ws, size_t ws_size,
                              hipStream_t stream) {
    const float* x  = (const float*)d_in[0];
    const float* S  = (const float*)d_in[1];
    const float* W1 = (const float*)d_in[2];
    const float* b1 = (const float*)d_in[3];
    const float* W2 = (const float*)d_in[4];
    const float* b2 = (const float*)d_in[5];
    const float* A1 = (const float*)d_in[6];
    const float* c1 = (const float*)d_in[7];
    const float* A2 = (const float*)d_in[8];
    const float* c2 = (const float*)d_in[9];
    float* out = (float*)d_out;

    char* ws = (char*)d_ws;
    const size_t SZ_Y1T = (size_t)BT_ * N_ * 64 * 2;   // 16,777,216 B per plane
    const size_t SZ_G   = (size_t)BT_ * 32 * N_ * 2;   //  8,388,608 B per plane
    const size_t SZ_H   = (size_t)BT_ * 32 * N_ * 4;   // 16,777,216 B (f32)
    const size_t SZ_T16 = (size_t)BT_ * N_ * 16 * 2;   //  4,194,304 B = ONE 16-row fp16 plane
    size_t off = 0;
    _Float16* Y1Th = (_Float16*)(ws + off); off += SZ_Y1T;
    _Float16* Y1Tl = (_Float16*)(ws + off); off += SZ_Y1T;
    _Float16* Gh   = (_Float16*)(ws + off); off += SZ_G;
    _Float16* Gl   = (_Float16*)(ws + off); off += SZ_G;
    float*    Hf   = (float*)(ws + off); off += SZ_H;
    float*    Y2a  = (float*)(ws + off); off += SZ_H;
    _Float16* Rh   = (_Float16*)(ws + off); off += SZ_G;
    _Float16* Rl   = (_Float16*)(ws + off); off += SZ_G;
    // small planes: each is SZ_T16 BYTES (units fix vs R15: was SZ_T16/2)
    _Float16* XTh  = (_Float16*)(ws + off); off += SZ_T16;
    _Float16* XTl  = (_Float16*)(ws + off); off += SZ_T16;
    _Float16* U1Th = (_Float16*)(ws + off); off += SZ_T16;
    _Float16* U1Tl = (_Float16*)(ws + off); off += SZ_T16;
    _Float16* V1Th = (_Float16*)(ws + off); off += SZ_T16;
    _Float16* V1Tl = (_Float16*)(ws + off); off += SZ_T16;
    _Float16* U1h  = (_Float16*)(ws + off); off += SZ_T16;
    _Float16* U1l  = (_Float16*)(ws + off); off += SZ_T16;
    if (ws_size < off) return;  // insufficient scratch -> clean failure

    k_u1<<<dim3(BT_, 4), 256, 0, stream>>>(S, x, U1h, U1l, U1Th, U1Tl);
    k_transpose_x<<<BT_, 256, 0, stream>>>(x, XTh, XTl);
    k_chainV1<<<dim3(BT_, 2), 256, 0, stream>>>(U1h, U1l, S, V1Th, V1Tl);
    k_combine1<<<BT_, 256, 0, stream>>>(XTh, XTl, U1Th, U1Tl, V1Th, V1Tl, W1, b1, Y1Th, Y1Tl);
    k_proj<<<BT_, 256, 0, stream>>>(Y1Th, Y1Tl, W2, Gh, Gl, Hf, Y2a);
    k_chainR<<<dim3(BT_, 2), 256, 0, stream>>>(Gh, Gl, S, Hf, Rh, Rl);
    k_chainY2<<<dim3(BT_, 2), 256, 0, stream>>>(Rh, Rl, S, Y2a, b2,
                                                A1, c1, A2, c2, out);
}